// Round 10
// baseline (375.937 us; speedup 1.0000x reference)
//
#include <hip/hip_runtime.h>
#include <hip/hip_bf16.h>

#define DFEAT 64
#define NBSH  8        // bucket = dst >> 8  (256 nodes per bucket)
#define NPB   256      // nodes per bucket
#define EPB   8192     // edges per partition block

// ---- A: per-block bucket histogram (LDS); blkhistT layout [bucket][block] ----
__global__ __launch_bounds__(256) void histA_kernel(const int* __restrict__ ei,
                                                    int* __restrict__ blkhistT,
                                                    int E, int nblk) {
    __shared__ int h[512];
    int t = threadIdx.x;
    h[t] = 0; h[t + 256] = 0;
    __syncthreads();
    int base = blockIdx.x * EPB;
    #pragma unroll
    for (int i = 0; i < EPB / 256; ++i) {
        int e = base + i * 256 + t;
        if (e < E) atomicAdd(&h[ei[E + e] >> NBSH], 1);
    }
    __syncthreads();
    blkhistT[t * nblk + blockIdx.x]         = h[t];
    blkhistT[(t + 256) * nblk + blockIdx.x] = h[t + 256];
}

// ---- B1: per-bucket exclusive scan over blocks (512 blocks, contiguous rows) ----
__global__ __launch_bounds__(256) void scanB1_kernel(int* __restrict__ blkhistT,
                                                     int* __restrict__ buckettotal, int nblk) {
    __shared__ int lds[256];
    int t = threadIdx.x;
    int b = blockIdx.x;
    int v = (t < nblk) ? blkhistT[b * nblk + t] : 0;
    lds[t] = v;
    __syncthreads();
    #pragma unroll
    for (int off = 1; off < 256; off <<= 1) {
        int y = (t >= off) ? lds[t - off] : 0;
        __syncthreads();
        lds[t] += y;
        __syncthreads();
    }
    if (t < nblk) blkhistT[b * nblk + t] = lds[t] - v;   // block-local base
    if (t == 255) buckettotal[b] = lds[255];
}

// ---- B2: single block, exclusive scan of 512 bucket totals ----
__global__ __launch_bounds__(512) void scanB2_kernel(const int* __restrict__ buckettotal,
                                                     int* __restrict__ bucketbase) {
    __shared__ int lds[512];
    int t = threadIdx.x;
    int s = buckettotal[t];
    lds[t] = s;
    __syncthreads();
    #pragma unroll
    for (int off = 1; off < 512; off <<= 1) {
        int y = (t >= off) ? lds[t - off] : 0;
        __syncthreads();
        lds[t] += y;
        __syncthreads();
    }
    bucketbase[t] = lds[t] - s;
    if (t == 511) bucketbase[512] = lds[511];
}

// ---- C: partition edges into buckets; pack (dst&255)<<17 | src (4B/edge) ----
__global__ __launch_bounds__(256) void partC_kernel(const int* __restrict__ ei,
                                                    const int* __restrict__ blkhistT,
                                                    const int* __restrict__ bucketbase,
                                                    unsigned* __restrict__ ebuf, int E, int nblk) {
    __shared__ int cur[512];
    int t = threadIdx.x;
    cur[t]       = bucketbase[t]       + blkhistT[t * nblk + blockIdx.x];
    cur[t + 256] = bucketbase[t + 256] + blkhistT[(t + 256) * nblk + blockIdx.x];
    __syncthreads();
    int base = blockIdx.x * EPB;
    #pragma unroll
    for (int i = 0; i < EPB / 256; ++i) {
        int e = base + i * 256 + t;
        if (e < E) {
            int s = ei[e];
            int d = ei[E + e];
            int pos = atomicAdd(&cur[d >> NBSH], 1);
            ebuf[pos] = (unsigned)s | ((unsigned)(d & (NPB - 1)) << 17);
        }
    }
}

// ---- D: per-bucket CSR build in LDS + fused dinv + bf16 xs pack ----
// Segment layout per node: [self][edges...][sentinels to pad len to x4]
__global__ __launch_bounds__(256) void csrD_kernel(const unsigned* __restrict__ ebuf,
                                                   const int* __restrict__ bucketbase,
                                                   const float* __restrict__ x,
                                                   int* __restrict__ srcs,
                                                   int* __restrict__ begs,
                                                   int* __restrict__ lens,
                                                   float* __restrict__ dinv,
                                                   unsigned* __restrict__ xs, int n) {
    __shared__ int cnt[256];
    __shared__ int tmp[256];
    __shared__ float dl[256];
    int t = threadIdx.x;
    int b = blockIdx.x;
    int ebeg = bucketbase[b], eend = bucketbase[b + 1];
    int regionbase = ebeg + b * (4 * NPB);     // +4 pad slots per node
    cnt[t] = 0;
    __syncthreads();
    for (int e = ebeg + t; e < eend; e += 256)
        atomicAdd(&cnt[ebuf[e] >> 17], 1);
    __syncthreads();
    int nid = (b << NBSH) + t;
    int deg = cnt[t];
    int slots = (nid < n) ? ((deg + 4) & ~3) : 0;
    tmp[t] = slots;
    __syncthreads();
    int s = slots;
    for (int o = 1; o < 256; o <<= 1) {
        int y = (t >= o) ? tmp[t - o] : 0;
        __syncthreads();
        tmp[t] += y;
        __syncthreads();
    }
    int excl = tmp[t] - s;
    float di = rsqrtf((float)(deg + 1));
    dl[t] = di;
    if (nid < n) {
        int beg_abs = regionbase + excl;
        begs[nid] = beg_abs;
        lens[nid] = slots;
        dinv[nid] = di;
        srcs[beg_abs] = nid;                            // self-loop slot
        for (int k = deg + 1; k < slots; ++k) srcs[beg_abs + k] = n;  // sentinels
    }
    cnt[t] = excl + 1;                                  // cursor past self slot
    __syncthreads();                                    // (also publishes dl[])
    for (int e = ebeg + t; e < eend; e += 256) {
        unsigned v = ebuf[e];
        int pos = atomicAdd(&cnt[v >> 17], 1);
        srcs[regionbase + pos] = (int)(v & 0x1ffffu);
    }
    // fused xs pack for this bucket's 256 nodes (+ zero row for node n)
    int base_nid = b << NBSH;
    for (int f = t; f < NPB * 32; f += 256) {
        int rr = f >> 5, c = f & 31;
        int node = base_nid + rr;
        if (node > n) continue;
        unsigned v = 0;
        if (node < n) {
            float dd = dl[rr];
            float f0 = x[node * DFEAT + 2 * c] * dd;
            float f1 = x[node * DFEAT + 2 * c + 1] * dd;
            unsigned u0 = __float_as_uint(f0); u0 = (u0 + 0x7fffu + ((u0 >> 16) & 1u)) >> 16;
            unsigned u1 = __float_as_uint(f1); u1 = (u1 + 0x7fffu + ((u1 >> 16) & 1u)) >> 16;
            v = (u0 & 0xffffu) | (u1 << 16);
        }
        xs[node * 32 + c] = v;    // node==n -> zero sentinel row
    }
}

// ---- Persistent fused QUAD-STREAM gather (uint2, 4 edge-groups) -> shared GEMM
//      (+bias) -> expmap0 -> proj. Each wave: 4 nodes in flight (max MLP).
__global__ __launch_bounds__(256) void agg_kernel(const int* __restrict__ begs,
                                                  const int* __restrict__ lens,
                                                  const int* __restrict__ srcs,
                                                  const float* __restrict__ dinv,
                                                  const uint2* __restrict__ xs2,
                                                  const float* __restrict__ W,
                                                  const float* __restrict__ b,
                                                  float* __restrict__ out,
                                                  int n, int ngroups) {
    __shared__ float Wl[DFEAT * DFEAT];    // 16 KB
    __shared__ float xl[4][4][DFEAT];      // 4 KB: [wave][stream][feat]
    int t = threadIdx.x;
    #pragma unroll
    for (int i = 0; i < 16; ++i) Wl[i * 256 + t] = W[i * 256 + t];
    __syncthreads();   // the ONLY barrier

    int r = t >> 6, lane = t & 63;
    int g = lane >> 4;        // edge group (0..3)
    int q = lane & 15;        // uint2 column -> features 4q..4q+3
    float bias = b[lane];

    for (int grp = blockIdx.x; grp < ngroups; grp += gridDim.x) {
        int node0 = grp * 16 + r;            // streams: node0 + 4*s
        float acc[4][4];
        #pragma unroll
        for (int s = 0; s < 4; ++s)
            #pragma unroll
            for (int i = 0; i < 4; ++i) acc[s][i] = 0.0f;

        int bases[4], ends[4];
        bool valid[4];
        #pragma unroll
        for (int s = 0; s < 4; ++s) {
            int node = node0 + 4 * s;
            valid[s] = node < n;
            if (valid[s]) { bases[s] = begs[node]; ends[s] = bases[s] + lens[node]; }
            else          { bases[s] = 0;          ends[s] = 0; }
        }

        while (bases[0] < ends[0] || bases[1] < ends[1] ||
               bases[2] < ends[2] || bases[3] < ends[3]) {
            int idx[4], qq[4];
            #pragma unroll
            for (int s = 0; s < 4; ++s) {
                int m = ends[s] - bases[s];
                m = m < 0 ? 0 : (m > 64 ? 64 : m);     // multiple of 4
                qq[s] = m >> 2;
                idx[s] = (lane < m) ? srcs[bases[s] + lane] : 0;
            }
            int qmax = max(max(qq[0], qq[1]), max(qq[2], qq[3]));
            for (int j = 0; j < qmax; ++j) {
                #pragma unroll
                for (int s = 0; s < 4; ++s) {
                    if (j < qq[s]) {                   // wave-uniform guard
                        int sv = __shfl(idx[s], 4 * j + g, 64);
                        uint2 d = xs2[(unsigned)sv * 16 + q];
                        acc[s][0] += __uint_as_float(d.x << 16);
                        acc[s][1] += __uint_as_float(d.x & 0xffff0000u);
                        acc[s][2] += __uint_as_float(d.y << 16);
                        acc[s][3] += __uint_as_float(d.y & 0xffff0000u);
                    }
                }
            }
            #pragma unroll
            for (int s = 0; s < 4; ++s) bases[s] += 64;
        }

        // reduce across the 4 edge-groups (lane bits 4..5)
        #pragma unroll
        for (int off = 16; off < 64; off <<= 1)
            #pragma unroll
            for (int s = 0; s < 4; ++s)
                #pragma unroll
                for (int i = 0; i < 4; ++i)
                    acc[s][i] += __shfl_xor(acc[s][i], off, 64);

        if (g == 0) {
            #pragma unroll
            for (int s = 0; s < 4; ++s)
                if (valid[s]) {
                    float di = dinv[node0 + 4 * s];
                    xl[r][s][4 * q + 0] = acc[s][0] * di;
                    xl[r][s][4 * q + 1] = acc[s][1] * di;
                    xl[r][s][4 * q + 2] = acc[s][2] * di;
                    xl[r][s][4 * q + 3] = acc[s][3] * di;
                }
        }
        // wave-synchronous LDS: same wave wrote xl[r][*], same wave reads it.

        float o[4];
        #pragma unroll
        for (int s = 0; s < 4; ++s) o[s] = bias;
        #pragma unroll
        for (int k = 0; k < DFEAT; ++k) {
            float w = Wl[k * DFEAT + lane];
            #pragma unroll
            for (int s = 0; s < 4; ++s) o[s] = fmaf(xl[r][s][k], w, o[s]);
        }

        #pragma unroll
        for (int s = 0; s < 4; ++s) {
            float ss = o[s] * o[s];
            #pragma unroll
            for (int off = 32; off > 0; off >>= 1) ss += __shfl_xor(ss, off, 64);
            float norm = fmaxf(sqrtf(ss), 1e-15f);
            float sc = fminf(tanhf(norm), 1.0f - 4e-3f) / norm;
            if (valid[s])
                out[(long long)(node0 + 4 * s) * DFEAT + lane] = o[s] * sc;
        }
    }
}

// ---------------- launch ----------------

extern "C" void kernel_launch(void* const* d_in, const int* in_sizes, int n_in,
                              void* d_out, int out_size, void* d_ws, size_t ws_size,
                              hipStream_t stream) {
    const float* x = (const float*)d_in[0];
    const float* W = (const float*)d_in[1];
    const float* b = (const float*)d_in[2];
    const int* ei  = (const int*)d_in[3];

    int n = in_sizes[0] / DFEAT;           // 100000
    int E = in_sizes[3] / 2;               // 1200000
    int NB = (n + NPB - 1) / NPB;          // 391 buckets
    int nblk = (E + EPB - 1) / EPB;        // 147 partition blocks
    int ngroups = (n + 15) / 16;           // 6250 (16 nodes per wave-quad group)

    // workspace layout (ints), ~25.5 MB total; xs separate from ebuf
    int* blkhistT    = (int*)d_ws;                         // 512*nblk
    int* buckettotal = blkhistT + 512 * nblk;              // 512
    int* bucketbase  = buckettotal + 512;                  // 513 (+pad to 516)
    int* srcs        = bucketbase + 516;                   // E + NB*4*NPB
    int* begs        = srcs + E + NB * 4 * NPB;            // n
    int* lens        = begs + n;                           // n
    float* dinv      = (float*)(lens + n);                 // n
    size_t xsoff     = (size_t)(((int*)dinv + n) - (int*)d_ws);
    xsoff            = (xsoff + 31) & ~(size_t)31;         // 128B-align
    unsigned* xs     = (unsigned*)d_ws + xsoff;            // (n+1)*32
    unsigned* ebuf   = xs + (size_t)(n + 1) * 32;          // E

    float* out = (float*)d_out;

    // LDS = 16K (Wl) + 4K (xl) -> 7 blocks/CU; persistent grid = 7*256
    int aggblocks = 1792;
    if (aggblocks > ngroups) aggblocks = ngroups;

    histA_kernel <<<nblk, 256, 0, stream>>>(ei, blkhistT, E, nblk);
    scanB1_kernel<<<512, 256, 0, stream>>>(blkhistT, buckettotal, nblk);
    scanB2_kernel<<<1, 512, 0, stream>>>(buckettotal, bucketbase);
    partC_kernel <<<nblk, 256, 0, stream>>>(ei, blkhistT, bucketbase, ebuf, E, nblk);
    csrD_kernel  <<<NB, 256, 0, stream>>>(ebuf, bucketbase, x, srcs, begs, lens, dinv, xs, n);
    agg_kernel   <<<aggblocks, 256, 0, stream>>>(begs, lens, srcs, dinv,
                                                 (const uint2*)xs, W, b, out, n, ngroups);
}

// Round 11
// 204.765 us; speedup vs baseline: 1.8359x; 1.8359x over previous
//
#include <hip/hip_runtime.h>
#include <hip/hip_bf16.h>

#define DFEAT 64
#define NBSH  8        // bucket = dst >> 8  (256 nodes per bucket)
#define NPB   256      // nodes per bucket
#define EPB   8192     // edges per partition block

// ---- A: per-block bucket histogram (LDS); blkhistT layout [bucket][block] ----
__global__ __launch_bounds__(256) void histA_kernel(const int* __restrict__ ei,
                                                    int* __restrict__ blkhistT,
                                                    int E, int nblk) {
    __shared__ int h[512];
    int t = threadIdx.x;
    h[t] = 0; h[t + 256] = 0;
    __syncthreads();
    int base = blockIdx.x * EPB;
    #pragma unroll
    for (int i = 0; i < EPB / 256; ++i) {
        int e = base + i * 256 + t;
        if (e < E) atomicAdd(&h[ei[E + e] >> NBSH], 1);
    }
    __syncthreads();
    blkhistT[t * nblk + blockIdx.x]         = h[t];
    blkhistT[(t + 256) * nblk + blockIdx.x] = h[t + 256];
}

// ---- B1: per-bucket exclusive scan over blocks (512 blocks, contiguous rows) ----
__global__ __launch_bounds__(256) void scanB1_kernel(int* __restrict__ blkhistT,
                                                     int* __restrict__ buckettotal, int nblk) {
    __shared__ int lds[256];
    int t = threadIdx.x;
    int b = blockIdx.x;
    int v = (t < nblk) ? blkhistT[b * nblk + t] : 0;
    lds[t] = v;
    __syncthreads();
    #pragma unroll
    for (int off = 1; off < 256; off <<= 1) {
        int y = (t >= off) ? lds[t - off] : 0;
        __syncthreads();
        lds[t] += y;
        __syncthreads();
    }
    if (t < nblk) blkhistT[b * nblk + t] = lds[t] - v;   // block-local base
    if (t == 255) buckettotal[b] = lds[255];
}

// ---- B2: single block, exclusive scan of 512 bucket totals ----
__global__ __launch_bounds__(512) void scanB2_kernel(const int* __restrict__ buckettotal,
                                                     int* __restrict__ bucketbase) {
    __shared__ int lds[512];
    int t = threadIdx.x;
    int s = buckettotal[t];
    lds[t] = s;
    __syncthreads();
    #pragma unroll
    for (int off = 1; off < 512; off <<= 1) {
        int y = (t >= off) ? lds[t - off] : 0;
        __syncthreads();
        lds[t] += y;
        __syncthreads();
    }
    bucketbase[t] = lds[t] - s;
    if (t == 511) bucketbase[512] = lds[511];
}

// ---- C: partition edges into buckets; pack (dst&255)<<17 | src (4B/edge) ----
__global__ __launch_bounds__(256) void partC_kernel(const int* __restrict__ ei,
                                                    const int* __restrict__ blkhistT,
                                                    const int* __restrict__ bucketbase,
                                                    unsigned* __restrict__ ebuf, int E, int nblk) {
    __shared__ int cur[512];
    int t = threadIdx.x;
    cur[t]       = bucketbase[t]       + blkhistT[t * nblk + blockIdx.x];
    cur[t + 256] = bucketbase[t + 256] + blkhistT[(t + 256) * nblk + blockIdx.x];
    __syncthreads();
    int base = blockIdx.x * EPB;
    #pragma unroll
    for (int i = 0; i < EPB / 256; ++i) {
        int e = base + i * 256 + t;
        if (e < E) {
            int s = ei[e];
            int d = ei[E + e];
            int pos = atomicAdd(&cur[d >> NBSH], 1);
            ebuf[pos] = (unsigned)s | ((unsigned)(d & (NPB - 1)) << 17);
        }
    }
}

// ---- D: per-bucket CSR build in LDS + fused dinv + bf16 xs pack ----
// Segment layout per node: [self][edges...][sentinels to pad len to x4]
__global__ __launch_bounds__(256) void csrD_kernel(const unsigned* __restrict__ ebuf,
                                                   const int* __restrict__ bucketbase,
                                                   const float* __restrict__ x,
                                                   int* __restrict__ srcs,
                                                   int* __restrict__ begs,
                                                   int* __restrict__ lens,
                                                   float* __restrict__ dinv,
                                                   unsigned* __restrict__ xs, int n) {
    __shared__ int cnt[256];
    __shared__ int tmp[256];
    __shared__ float dl[256];
    int t = threadIdx.x;
    int b = blockIdx.x;
    int ebeg = bucketbase[b], eend = bucketbase[b + 1];
    int regionbase = ebeg + b * (4 * NPB);     // +4 pad slots per node
    cnt[t] = 0;
    __syncthreads();
    for (int e = ebeg + t; e < eend; e += 256)
        atomicAdd(&cnt[ebuf[e] >> 17], 1);
    __syncthreads();
    int nid = (b << NBSH) + t;
    int deg = cnt[t];
    int slots = (nid < n) ? ((deg + 4) & ~3) : 0;
    tmp[t] = slots;
    __syncthreads();
    int s = slots;
    for (int o = 1; o < 256; o <<= 1) {
        int y = (t >= o) ? tmp[t - o] : 0;
        __syncthreads();
        tmp[t] += y;
        __syncthreads();
    }
    int excl = tmp[t] - s;
    float di = rsqrtf((float)(deg + 1));
    dl[t] = di;
    if (nid < n) {
        int beg_abs = regionbase + excl;
        begs[nid] = beg_abs;
        lens[nid] = slots;
        dinv[nid] = di;
        srcs[beg_abs] = nid;                            // self-loop slot
        for (int k = deg + 1; k < slots; ++k) srcs[beg_abs + k] = n;  // sentinels
    }
    cnt[t] = excl + 1;                                  // cursor past self slot
    __syncthreads();                                    // (also publishes dl[])
    for (int e = ebeg + t; e < eend; e += 256) {
        unsigned v = ebuf[e];
        int pos = atomicAdd(&cnt[v >> 17], 1);
        srcs[regionbase + pos] = (int)(v & 0x1ffffu);
    }
    // fused xs pack for this bucket's 256 nodes (+ zero row for node n)
    int base_nid = b << NBSH;
    for (int f = t; f < NPB * 32; f += 256) {
        int rr = f >> 5, c = f & 31;
        int node = base_nid + rr;
        if (node > n) continue;
        unsigned v = 0;
        if (node < n) {
            float dd = dl[rr];
            float f0 = x[node * DFEAT + 2 * c] * dd;
            float f1 = x[node * DFEAT + 2 * c + 1] * dd;
            unsigned u0 = __float_as_uint(f0); u0 = (u0 + 0x7fffu + ((u0 >> 16) & 1u)) >> 16;
            unsigned u1 = __float_as_uint(f1); u1 = (u1 + 0x7fffu + ((u1 >> 16) & 1u)) >> 16;
            v = (u0 & 0xffffu) | (u1 << 16);
        }
        xs[node * 32 + c] = v;    // node==n -> zero sentinel row
    }
}

// ---- Persistent fused DUAL-NODE gather -> shared GEMM(+bias) -> expmap0 -> proj ----
// R8-proven structure: 2 nodes/wave, named scalars only (VGPR ~36, 8 waves/SIMD).
__global__ __launch_bounds__(256) void agg_kernel(const int* __restrict__ begs,
                                                  const int* __restrict__ lens,
                                                  const int* __restrict__ srcs,
                                                  const float* __restrict__ dinv,
                                                  const uint2* __restrict__ xs2,
                                                  const float* __restrict__ W,
                                                  const float* __restrict__ b,
                                                  float* __restrict__ out,
                                                  int n, int noctets) {
    __shared__ float Wl[DFEAT * DFEAT];   // 16 KB
    __shared__ float xl[8][DFEAT];        // 2 KB
    int t = threadIdx.x;
    #pragma unroll
    for (int i = 0; i < 16; ++i) Wl[i * 256 + t] = W[i * 256 + t];
    __syncthreads();   // the ONLY barrier

    int r = t >> 6, lane = t & 63;
    int g = lane >> 4;        // edge group (0..3)
    int q = lane & 15;        // uint2 column -> features 4q..4q+3
    float bias = b[lane];

    for (int oct = blockIdx.x; oct < noctets; oct += gridDim.x) {
        int na = oct * 8 + r;
        int nb_ = na + 4;
        bool va = na < n, vb = nb_ < n;
        if (!va) continue;

        int beg0 = begs[na],  end0 = beg0 + lens[na];
        int beg1 = 0, end1 = 0;
        if (vb) { beg1 = begs[nb_]; end1 = beg1 + lens[nb_]; }

        float a0 = 0, a1 = 0, a2 = 0, a3 = 0;
        float b0 = 0, b1 = 0, b2 = 0, b3 = 0;
        int base0 = beg0, base1 = beg1;
        while (base0 < end0 || base1 < end1) {
            int m0 = end0 - base0; m0 = m0 < 0 ? 0 : (m0 > 64 ? 64 : m0);
            int m1 = end1 - base1; m1 = m1 < 0 ? 0 : (m1 > 64 ? 64 : m1);
            int idx0 = 0, idx1 = 0;
            if (lane < m0) idx0 = srcs[base0 + lane];
            if (lane < m1) idx1 = srcs[base1 + lane];
            int q0 = m0 >> 2, q1 = m1 >> 2;
            int qc = q0 < q1 ? q0 : q1;
            for (int j = 0; j < qc; ++j) {
                int sv0 = __shfl(idx0, 4 * j + g, 64);
                int sv1 = __shfl(idx1, 4 * j + g, 64);
                uint2 d0 = xs2[(unsigned)sv0 * 16 + q];
                uint2 d1 = xs2[(unsigned)sv1 * 16 + q];
                a0 += __uint_as_float(d0.x << 16);
                a1 += __uint_as_float(d0.x & 0xffff0000u);
                a2 += __uint_as_float(d0.y << 16);
                a3 += __uint_as_float(d0.y & 0xffff0000u);
                b0 += __uint_as_float(d1.x << 16);
                b1 += __uint_as_float(d1.x & 0xffff0000u);
                b2 += __uint_as_float(d1.y << 16);
                b3 += __uint_as_float(d1.y & 0xffff0000u);
            }
            for (int j = qc; j < q0; ++j) {
                int sv0 = __shfl(idx0, 4 * j + g, 64);
                uint2 d0 = xs2[(unsigned)sv0 * 16 + q];
                a0 += __uint_as_float(d0.x << 16);
                a1 += __uint_as_float(d0.x & 0xffff0000u);
                a2 += __uint_as_float(d0.y << 16);
                a3 += __uint_as_float(d0.y & 0xffff0000u);
            }
            for (int j = qc; j < q1; ++j) {
                int sv1 = __shfl(idx1, 4 * j + g, 64);
                uint2 d1 = xs2[(unsigned)sv1 * 16 + q];
                b0 += __uint_as_float(d1.x << 16);
                b1 += __uint_as_float(d1.x & 0xffff0000u);
                b2 += __uint_as_float(d1.y << 16);
                b3 += __uint_as_float(d1.y & 0xffff0000u);
            }
            base0 += 64; base1 += 64;
        }
        #pragma unroll
        for (int off = 16; off < 64; off <<= 1) {
            a0 += __shfl_xor(a0, off, 64);
            a1 += __shfl_xor(a1, off, 64);
            a2 += __shfl_xor(a2, off, 64);
            a3 += __shfl_xor(a3, off, 64);
            b0 += __shfl_xor(b0, off, 64);
            b1 += __shfl_xor(b1, off, 64);
            b2 += __shfl_xor(b2, off, 64);
            b3 += __shfl_xor(b3, off, 64);
        }
        if (g == 0) {
            float dia = dinv[na];
            xl[r][4 * q + 0] = a0 * dia;
            xl[r][4 * q + 1] = a1 * dia;
            xl[r][4 * q + 2] = a2 * dia;
            xl[r][4 * q + 3] = a3 * dia;
            if (vb) {
                float dib = dinv[nb_];
                xl[r + 4][4 * q + 0] = b0 * dib;
                xl[r + 4][4 * q + 1] = b1 * dib;
                xl[r + 4][4 * q + 2] = b2 * dib;
                xl[r + 4][4 * q + 3] = b3 * dib;
            }
        }
        // wave-synchronous LDS: same wave wrote xl rows r / r+4, same wave reads.

        float oa0 = bias, oa1 = 0.0f, ob0 = bias, ob1 = 0.0f;
        #pragma unroll
        for (int k = 0; k < DFEAT; k += 2) {
            float w0 = Wl[k * DFEAT + lane];
            float w1 = Wl[(k + 1) * DFEAT + lane];
            oa0 = fmaf(xl[r][k],     w0, oa0);
            oa1 = fmaf(xl[r][k + 1], w1, oa1);
            ob0 = fmaf(xl[r + 4][k],     w0, ob0);
            ob1 = fmaf(xl[r + 4][k + 1], w1, ob1);
        }
        float oa = oa0 + oa1;
        float ob = ob0 + ob1;

        float ssa = oa * oa, ssb = ob * ob;
        #pragma unroll
        for (int off = 32; off > 0; off >>= 1) {
            ssa += __shfl_xor(ssa, off, 64);
            ssb += __shfl_xor(ssb, off, 64);
        }
        float norma = fmaxf(sqrtf(ssa), 1e-15f);
        float sca = fminf(tanhf(norma), 1.0f - 4e-3f) / norma;
        out[(long long)na * DFEAT + lane] = oa * sca;
        if (vb) {
            float normb = fmaxf(sqrtf(ssb), 1e-15f);
            float scb = fminf(tanhf(normb), 1.0f - 4e-3f) / normb;
            out[(long long)nb_ * DFEAT + lane] = ob * scb;
        }
    }
}

// ---------------- launch ----------------

extern "C" void kernel_launch(void* const* d_in, const int* in_sizes, int n_in,
                              void* d_out, int out_size, void* d_ws, size_t ws_size,
                              hipStream_t stream) {
    const float* x = (const float*)d_in[0];
    const float* W = (const float*)d_in[1];
    const float* b = (const float*)d_in[2];
    const int* ei  = (const int*)d_in[3];

    int n = in_sizes[0] / DFEAT;           // 100000
    int E = in_sizes[3] / 2;               // 1200000
    int NB = (n + NPB - 1) / NPB;          // 391 buckets
    int nblk = (E + EPB - 1) / EPB;        // 147 partition blocks
    int noctets = (n + 7) / 8;             // 12500

    // workspace layout (ints), ~25.5 MB total; xs separate from ebuf
    int* blkhistT    = (int*)d_ws;                         // 512*nblk
    int* buckettotal = blkhistT + 512 * nblk;              // 512
    int* bucketbase  = buckettotal + 512;                  // 513 (+pad to 516)
    int* srcs        = bucketbase + 516;                   // E + NB*4*NPB
    int* begs        = srcs + E + NB * 4 * NPB;            // n
    int* lens        = begs + n;                           // n
    float* dinv      = (float*)(lens + n);                 // n
    size_t xsoff     = (size_t)(((int*)dinv + n) - (int*)d_ws);
    xsoff            = (xsoff + 31) & ~(size_t)31;         // 128B-align
    unsigned* xs     = (unsigned*)d_ws + xsoff;            // (n+1)*32
    unsigned* ebuf   = xs + (size_t)(n + 1) * 32;          // E

    float* out = (float*)d_out;

    int aggblocks = 2048;                  // 8 blocks/CU (LDS 18K -> 8/CU fits)
    if (aggblocks > noctets) aggblocks = noctets;

    histA_kernel <<<nblk, 256, 0, stream>>>(ei, blkhistT, E, nblk);
    scanB1_kernel<<<512, 256, 0, stream>>>(blkhistT, buckettotal, nblk);
    scanB2_kernel<<<1, 512, 0, stream>>>(buckettotal, bucketbase);
    partC_kernel <<<nblk, 256, 0, stream>>>(ei, blkhistT, bucketbase, ebuf, E, nblk);
    csrD_kernel  <<<NB, 256, 0, stream>>>(ebuf, bucketbase, x, srcs, begs, lens, dinv, xs, n);
    agg_kernel   <<<aggblocks, 256, 0, stream>>>(begs, lens, srcs, dinv,
                                                 (const uint2*)xs, W, b, out, n, noctets);
}

// Round 12
// 191.732 us; speedup vs baseline: 1.9607x; 1.0680x over previous
//
#include <hip/hip_runtime.h>
#include <hip/hip_bf16.h>

#define DFEAT 64
#define NBSH  8        // bucket = dst >> 8  (256 nodes per bucket)
#define NPB   256      // nodes per bucket
#define EPB   8192     // edges per partition block

// ---- A: per-block bucket histogram (LDS); blkhistT layout [bucket][block] ----
__global__ __launch_bounds__(256) void histA_kernel(const int* __restrict__ ei,
                                                    int* __restrict__ blkhistT,
                                                    int E, int nblk) {
    __shared__ int h[512];
    int t = threadIdx.x;
    h[t] = 0; h[t + 256] = 0;
    __syncthreads();
    int base = blockIdx.x * EPB;
    #pragma unroll
    for (int i = 0; i < EPB / 256; ++i) {
        int e = base + i * 256 + t;
        if (e < E) atomicAdd(&h[ei[E + e] >> NBSH], 1);
    }
    __syncthreads();
    blkhistT[t * nblk + blockIdx.x]         = h[t];
    blkhistT[(t + 256) * nblk + blockIdx.x] = h[t + 256];
}

// ---- B1: per-bucket exclusive scan over blocks (512 blocks, contiguous rows) ----
__global__ __launch_bounds__(256) void scanB1_kernel(int* __restrict__ blkhistT,
                                                     int* __restrict__ buckettotal, int nblk) {
    __shared__ int lds[256];
    int t = threadIdx.x;
    int b = blockIdx.x;
    int v = (t < nblk) ? blkhistT[b * nblk + t] : 0;
    lds[t] = v;
    __syncthreads();
    #pragma unroll
    for (int off = 1; off < 256; off <<= 1) {
        int y = (t >= off) ? lds[t - off] : 0;
        __syncthreads();
        lds[t] += y;
        __syncthreads();
    }
    if (t < nblk) blkhistT[b * nblk + t] = lds[t] - v;   // block-local base
    if (t == 255) buckettotal[b] = lds[255];
}

// ---- B2: single block, exclusive scan of 512 bucket totals ----
__global__ __launch_bounds__(512) void scanB2_kernel(const int* __restrict__ buckettotal,
                                                     int* __restrict__ bucketbase) {
    __shared__ int lds[512];
    int t = threadIdx.x;
    int s = buckettotal[t];
    lds[t] = s;
    __syncthreads();
    #pragma unroll
    for (int off = 1; off < 512; off <<= 1) {
        int y = (t >= off) ? lds[t - off] : 0;
        __syncthreads();
        lds[t] += y;
        __syncthreads();
    }
    bucketbase[t] = lds[t] - s;
    if (t == 511) bucketbase[512] = lds[511];
}

// ---- C: partition edges into buckets; pack (dst&255)<<17 | src (4B/edge) ----
__global__ __launch_bounds__(256) void partC_kernel(const int* __restrict__ ei,
                                                    const int* __restrict__ blkhistT,
                                                    const int* __restrict__ bucketbase,
                                                    unsigned* __restrict__ ebuf, int E, int nblk) {
    __shared__ int cur[512];
    int t = threadIdx.x;
    cur[t]       = bucketbase[t]       + blkhistT[t * nblk + blockIdx.x];
    cur[t + 256] = bucketbase[t + 256] + blkhistT[(t + 256) * nblk + blockIdx.x];
    __syncthreads();
    int base = blockIdx.x * EPB;
    #pragma unroll
    for (int i = 0; i < EPB / 256; ++i) {
        int e = base + i * 256 + t;
        if (e < E) {
            int s = ei[e];
            int d = ei[E + e];
            int pos = atomicAdd(&cur[d >> NBSH], 1);
            ebuf[pos] = (unsigned)s | ((unsigned)(d & (NPB - 1)) << 17);
        }
    }
}

// ---- D: per-bucket CSR build in LDS (single-writer srcs region) ----
// Segment layout per node: [self][edges...][sentinels to pad len to x4]
__global__ __launch_bounds__(256) void csrD_kernel(const unsigned* __restrict__ ebuf,
                                                   const int* __restrict__ bucketbase,
                                                   int* __restrict__ srcs,
                                                   int* __restrict__ begs,
                                                   int* __restrict__ lens,
                                                   float* __restrict__ dinv, int n) {
    __shared__ int cnt[256];
    __shared__ int tmp[256];
    int t = threadIdx.x;
    int b = blockIdx.x;
    int ebeg = bucketbase[b], eend = bucketbase[b + 1];
    int regionbase = ebeg + b * (4 * NPB);     // +4 pad slots per node
    cnt[t] = 0;
    __syncthreads();
    for (int e = ebeg + t; e < eend; e += 256)
        atomicAdd(&cnt[ebuf[e] >> 17], 1);
    __syncthreads();
    int nid = (b << NBSH) + t;
    int deg = cnt[t];
    int slots = (nid < n) ? ((deg + 4) & ~3) : 0;
    tmp[t] = slots;
    __syncthreads();
    int s = slots;
    for (int o = 1; o < 256; o <<= 1) {
        int y = (t >= o) ? tmp[t - o] : 0;
        __syncthreads();
        tmp[t] += y;
        __syncthreads();
    }
    int excl = tmp[t] - s;
    if (nid < n) {
        int beg_abs = regionbase + excl;
        begs[nid] = beg_abs;
        lens[nid] = slots;
        dinv[nid] = rsqrtf((float)(deg + 1));
        srcs[beg_abs] = nid;                            // self-loop slot
        for (int k = deg + 1; k < slots; ++k) srcs[beg_abs + k] = n;  // sentinels
    }
    cnt[t] = excl + 1;                                  // cursor past self slot
    __syncthreads();
    for (int e = ebeg + t; e < eend; e += 256) {
        unsigned v = ebuf[e];
        int pos = atomicAdd(&cnt[v >> 17], 1);
        srcs[regionbase + pos] = (int)(v & 0x1ffffu);
    }
}

// ---- xs[row] = bf16(x[row] * dinv[row]) packed 2/dword; row n = zeros ----
__global__ __launch_bounds__(256) void xsprep_kernel(const float* __restrict__ x,
                                                     const float* __restrict__ dinv,
                                                     unsigned* __restrict__ xs, int n) {
    int i = blockIdx.x * blockDim.x + threadIdx.x;
    int total = (n + 1) * 32;
    if (i >= total) return;
    int row = i >> 5, col = i & 31;
    unsigned v = 0;
    if (row < n) {
        float di = dinv[row];
        float f0 = x[row * DFEAT + 2 * col] * di;
        float f1 = x[row * DFEAT + 2 * col + 1] * di;
        unsigned u0 = __float_as_uint(f0); u0 = (u0 + 0x7fffu + ((u0 >> 16) & 1u)) >> 16;
        unsigned u1 = __float_as_uint(f1); u1 = (u1 + 0x7fffu + ((u1 >> 16) & 1u)) >> 16;
        v = (u0 & 0xffffu) | (u1 << 16);
    }
    xs[i] = v;
}

// ---- Persistent fused DUAL-NODE gather -> shared GEMM(+bias) -> expmap0 -> proj ----
// 2 nodes/wave (named scalars), inner gather loop unrolled 4x for MLP.
__global__ __launch_bounds__(256) void agg_kernel(const int* __restrict__ begs,
                                                  const int* __restrict__ lens,
                                                  const int* __restrict__ srcs,
                                                  const float* __restrict__ dinv,
                                                  const uint2* __restrict__ xs2,
                                                  const float* __restrict__ W,
                                                  const float* __restrict__ b,
                                                  float* __restrict__ out,
                                                  int n, int noctets) {
    __shared__ float Wl[DFEAT * DFEAT];   // 16 KB
    __shared__ float xl[8][DFEAT];        // 2 KB
    int t = threadIdx.x;
    #pragma unroll
    for (int i = 0; i < 16; ++i) Wl[i * 256 + t] = W[i * 256 + t];
    __syncthreads();   // the ONLY barrier

    int r = t >> 6, lane = t & 63;
    int g = lane >> 4;        // edge group (0..3)
    int q = lane & 15;        // uint2 column -> features 4q..4q+3
    float bias = b[lane];

    for (int oct = blockIdx.x; oct < noctets; oct += gridDim.x) {
        int na = oct * 8 + r;
        int nb_ = na + 4;
        bool va = na < n, vb = nb_ < n;
        if (!va) continue;

        int beg0 = begs[na],  end0 = beg0 + lens[na];
        int beg1 = 0, end1 = 0;
        if (vb) { beg1 = begs[nb_]; end1 = beg1 + lens[nb_]; }

        float a0 = 0, a1 = 0, a2 = 0, a3 = 0;
        float b0 = 0, b1 = 0, b2 = 0, b3 = 0;
        int base0 = beg0, base1 = beg1;
        while (base0 < end0 || base1 < end1) {
            int m0 = end0 - base0; m0 = m0 < 0 ? 0 : (m0 > 64 ? 64 : m0);
            int m1 = end1 - base1; m1 = m1 < 0 ? 0 : (m1 > 64 ? 64 : m1);
            int idx0 = 0, idx1 = 0;
            if (lane < m0) idx0 = srcs[base0 + lane];
            if (lane < m1) idx1 = srcs[base1 + lane];
            int q0 = m0 >> 2, q1 = m1 >> 2;
            int qc = q0 < q1 ? q0 : q1;
            #pragma unroll 4
            for (int j = 0; j < qc; ++j) {
                int sv0 = __shfl(idx0, 4 * j + g, 64);
                int sv1 = __shfl(idx1, 4 * j + g, 64);
                uint2 d0 = xs2[(unsigned)sv0 * 16 + q];
                uint2 d1 = xs2[(unsigned)sv1 * 16 + q];
                a0 += __uint_as_float(d0.x << 16);
                a1 += __uint_as_float(d0.x & 0xffff0000u);
                a2 += __uint_as_float(d0.y << 16);
                a3 += __uint_as_float(d0.y & 0xffff0000u);
                b0 += __uint_as_float(d1.x << 16);
                b1 += __uint_as_float(d1.x & 0xffff0000u);
                b2 += __uint_as_float(d1.y << 16);
                b3 += __uint_as_float(d1.y & 0xffff0000u);
            }
            #pragma unroll 4
            for (int j = qc; j < q0; ++j) {
                int sv0 = __shfl(idx0, 4 * j + g, 64);
                uint2 d0 = xs2[(unsigned)sv0 * 16 + q];
                a0 += __uint_as_float(d0.x << 16);
                a1 += __uint_as_float(d0.x & 0xffff0000u);
                a2 += __uint_as_float(d0.y << 16);
                a3 += __uint_as_float(d0.y & 0xffff0000u);
            }
            #pragma unroll 4
            for (int j = qc; j < q1; ++j) {
                int sv1 = __shfl(idx1, 4 * j + g, 64);
                uint2 d1 = xs2[(unsigned)sv1 * 16 + q];
                b0 += __uint_as_float(d1.x << 16);
                b1 += __uint_as_float(d1.x & 0xffff0000u);
                b2 += __uint_as_float(d1.y << 16);
                b3 += __uint_as_float(d1.y & 0xffff0000u);
            }
            base0 += 64; base1 += 64;
        }
        #pragma unroll
        for (int off = 16; off < 64; off <<= 1) {
            a0 += __shfl_xor(a0, off, 64);
            a1 += __shfl_xor(a1, off, 64);
            a2 += __shfl_xor(a2, off, 64);
            a3 += __shfl_xor(a3, off, 64);
            b0 += __shfl_xor(b0, off, 64);
            b1 += __shfl_xor(b1, off, 64);
            b2 += __shfl_xor(b2, off, 64);
            b3 += __shfl_xor(b3, off, 64);
        }
        if (g == 0) {
            float dia = dinv[na];
            xl[r][4 * q + 0] = a0 * dia;
            xl[r][4 * q + 1] = a1 * dia;
            xl[r][4 * q + 2] = a2 * dia;
            xl[r][4 * q + 3] = a3 * dia;
            if (vb) {
                float dib = dinv[nb_];
                xl[r + 4][4 * q + 0] = b0 * dib;
                xl[r + 4][4 * q + 1] = b1 * dib;
                xl[r + 4][4 * q + 2] = b2 * dib;
                xl[r + 4][4 * q + 3] = b3 * dib;
            }
        }
        // wave-synchronous LDS: same wave wrote xl rows r / r+4, same wave reads.

        float oa0 = bias, oa1 = 0.0f, ob0 = bias, ob1 = 0.0f;
        #pragma unroll
        for (int k = 0; k < DFEAT; k += 2) {
            float w0 = Wl[k * DFEAT + lane];
            float w1 = Wl[(k + 1) * DFEAT + lane];
            oa0 = fmaf(xl[r][k],     w0, oa0);
            oa1 = fmaf(xl[r][k + 1], w1, oa1);
            ob0 = fmaf(xl[r + 4][k],     w0, ob0);
            ob1 = fmaf(xl[r + 4][k + 1], w1, ob1);
        }
        float oa = oa0 + oa1;
        float ob = ob0 + ob1;

        float ssa = oa * oa, ssb = ob * ob;
        #pragma unroll
        for (int off = 32; off > 0; off >>= 1) {
            ssa += __shfl_xor(ssa, off, 64);
            ssb += __shfl_xor(ssb, off, 64);
        }
        float norma = fmaxf(sqrtf(ssa), 1e-15f);
        float sca = fminf(tanhf(norma), 1.0f - 4e-3f) / norma;
        out[(long long)na * DFEAT + lane] = oa * sca;
        if (vb) {
            float normb = fmaxf(sqrtf(ssb), 1e-15f);
            float scb = fminf(tanhf(normb), 1.0f - 4e-3f) / normb;
            out[(long long)nb_ * DFEAT + lane] = ob * scb;
        }
    }
}

// ---------------- launch ----------------

extern "C" void kernel_launch(void* const* d_in, const int* in_sizes, int n_in,
                              void* d_out, int out_size, void* d_ws, size_t ws_size,
                              hipStream_t stream) {
    const float* x = (const float*)d_in[0];
    const float* W = (const float*)d_in[1];
    const float* b = (const float*)d_in[2];
    const int* ei  = (const int*)d_in[3];

    int n = in_sizes[0] / DFEAT;           // 100000
    int E = in_sizes[3] / 2;               // 1200000
    int NB = (n + NPB - 1) / NPB;          // 391 buckets
    int nblk = (E + EPB - 1) / EPB;        // 147 partition blocks
    int noctets = (n + 7) / 8;             // 12500

    // workspace layout (ints), ~25.5 MB total; xs separate from ebuf
    int* blkhistT    = (int*)d_ws;                         // 512*nblk
    int* buckettotal = blkhistT + 512 * nblk;              // 512
    int* bucketbase  = buckettotal + 512;                  // 513 (+pad to 516)
    int* srcs        = bucketbase + 516;                   // E + NB*4*NPB
    int* begs        = srcs + E + NB * 4 * NPB;            // n
    int* lens        = begs + n;                           // n
    float* dinv      = (float*)(lens + n);                 // n
    size_t xsoff     = (size_t)(((int*)dinv + n) - (int*)d_ws);
    xsoff            = (xsoff + 31) & ~(size_t)31;         // 128B-align
    unsigned* xs     = (unsigned*)d_ws + xsoff;            // (n+1)*32
    unsigned* ebuf   = xs + (size_t)(n + 1) * 32;          // E

    float* out = (float*)d_out;

    int aggblocks = 2048;                  // 8 blocks/CU (LDS 18K)
    if (aggblocks > noctets) aggblocks = noctets;

    histA_kernel <<<nblk, 256, 0, stream>>>(ei, blkhistT, E, nblk);
    scanB1_kernel<<<512, 256, 0, stream>>>(blkhistT, buckettotal, nblk);
    scanB2_kernel<<<1, 512, 0, stream>>>(buckettotal, bucketbase);
    partC_kernel <<<nblk, 256, 0, stream>>>(ei, blkhistT, bucketbase, ebuf, E, nblk);
    csrD_kernel  <<<NB, 256, 0, stream>>>(ebuf, bucketbase, srcs, begs, lens, dinv, n);
    xsprep_kernel<<<((n + 1) * 32 + 255) / 256, 256, 0, stream>>>(x, dinv, xs, n);
    agg_kernel   <<<aggblocks, 256, 0, stream>>>(begs, lens, srcs, dinv,
                                                 (const uint2*)xs, W, b, out, n, noctets);
}